// Round 7
// baseline (167.643 us; speedup 1.0000x reference)
//
#include <hip/hip_runtime.h>
#include <cstddef>

#define S_LEN 4096
#define C_DIM 256
#define NHEADS 8
#define HDIM 32

typedef __attribute__((ext_vector_type(8))) _Float16 half8;
typedef __attribute__((ext_vector_type(4))) _Float16 half4;
typedef __attribute__((ext_vector_type(2))) _Float16 h2t;
typedef __attribute__((ext_vector_type(2))) __fp16 fp16x2;
typedef __attribute__((ext_vector_type(4))) float floatx4;

// scale * log2(e) folded into W_q and bias_q at prep time
#define SC2F ((float)(0.17677669529663687 * 1.4426950408889634))

// ---------------------------------------------------------------- prep + GN stats (fused)
__global__ __launch_bounds__(256) void prep_stats(
    const float* __restrict__ qkv_w, const float* __restrict__ proj_w,
    const float* __restrict__ qkv_b, const float* __restrict__ x,
    _Float16* __restrict__ wq, _Float16* __restrict__ wp,
    float* __restrict__ qbias, float* __restrict__ gstat)
{
  const int blk = blockIdx.x;
  const int tid = threadIdx.x;
  if (blk < 64) {
    __shared__ float red[2][4];
    const int g = blk & 31, b = blk >> 5;
    const float* xb = x + ((size_t)b * C_DIM + g * 8) * S_LEN;
    const float4* x4 = (const float4*)xb;
    float sum = 0.f, sumsq = 0.f;
    for (int i = tid; i < 8192; i += 256) {
      float4 v = x4[i];
      sum += v.x + v.y + v.z + v.w;
      sumsq += v.x * v.x + v.y * v.y + v.z * v.z + v.w * v.w;
    }
    for (int off = 1; off < 64; off <<= 1) {
      sum += __shfl_xor(sum, off, 64);
      sumsq += __shfl_xor(sumsq, off, 64);
    }
    const int wv = tid >> 6, lane = tid & 63;
    if (lane == 0) { red[0][wv] = sum; red[1][wv] = sumsq; }
    __syncthreads();
    if (tid == 0) {
      float s = red[0][0] + red[0][1] + red[0][2] + red[0][3];
      float sq = red[1][0] + red[1][1] + red[1][2] + red[1][3];
      float mean = s * (1.f / 32768.f);
      float var = sq * (1.f / 32768.f) - mean * mean;
      gstat[((size_t)b * 32 + g) * 2 + 0] = mean;
      gstat[((size_t)b * 32 + g) * 2 + 1] = rsqrtf(var + 1e-6f);
    }
  } else {
    int idx = (blk - 64) * 256 + tid;
    if (idx < 768 * 256) {
      float v = qkv_w[idx];
      if (idx < 256 * 256) v *= SC2F;          // q rows
      wq[idx] = (_Float16)v;
    } else if (idx < 768 * 256 + 256 * 256) {
      int i = idx - 768 * 256;
      wp[i] = (_Float16)proj_w[i];
    } else if (idx < 768 * 256 + 256 * 256 + 768) {
      int i = idx - (768 * 256 + 256 * 256);
      float bv = qkv_b[i];
      if (i < 256) bv *= SC2F;
      qbias[i] = bv;
    }
  }
}

// ---------------------------------------------------------------- QKV GEMM + inline GN
// Wave owns 4 mt-tiles (64 W-rows): B-frags read once per K-step feed 16
// MFMAs. blockIdx.x: 3 (x-tile GN redundancy 3x instead of 12x).
__global__ __launch_bounds__(256) void qkv_gn_gemm(
    const _Float16* __restrict__ W, const float* __restrict__ bias,
    const float* __restrict__ x, const float* __restrict__ gamma,
    const float* __restrict__ beta, const float* __restrict__ gstat,
    _Float16* __restrict__ qo, _Float16* __restrict__ ko_,
    _Float16* __restrict__ vo)
{
  __shared__ __align__(16) _Float16 Ld[64 * 264];   // [s][c], stride 264
  const int tid = threadIdx.x;
  const int b = blockIdx.z;
  const int s0 = blockIdx.y * 64;

  {  // ---- inline GN apply: x (c,s) -> Ld[s][c] f16
    const int c0 = (tid & 127) * 2, c1 = c0 + 1;
    const int sh = tid >> 7;                         // s-half 0/1
    const int g = c0 >> 3;
    const float mean = gstat[((size_t)b * 32 + g) * 2 + 0];
    const float rstd = gstat[((size_t)b * 32 + g) * 2 + 1];
    const float ga0 = gamma[c0] * rstd, be0 = beta[c0] - mean * ga0;
    const float ga1 = gamma[c1] * rstd, be1 = beta[c1] - mean * ga1;
    const float4* xa = (const float4*)(x + ((size_t)b * C_DIM + c0) * S_LEN + s0 + sh * 32);
    const float4* xc = (const float4*)(x + ((size_t)b * C_DIM + c1) * S_LEN + s0 + sh * 32);
    #pragma unroll
    for (int j = 0; j < 8; ++j) {
      float4 a = xa[j], c = xc[j];
      int sl = sh * 32 + j * 4;
      *(h2t*)&Ld[(sl + 0) * 264 + c0] = (h2t){ (_Float16)(a.x * ga0 + be0), (_Float16)(c.x * ga1 + be1) };
      *(h2t*)&Ld[(sl + 1) * 264 + c0] = (h2t){ (_Float16)(a.y * ga0 + be0), (_Float16)(c.y * ga1 + be1) };
      *(h2t*)&Ld[(sl + 2) * 264 + c0] = (h2t){ (_Float16)(a.z * ga0 + be0), (_Float16)(c.z * ga1 + be1) };
      *(h2t*)&Ld[(sl + 3) * 264 + c0] = (h2t){ (_Float16)(a.w * ga0 + be0), (_Float16)(c.w * ga1 + be1) };
    }
  }
  __syncthreads();

  const int lane = tid & 63, wv = tid >> 6;
  const int m = lane & 15, quad = lane >> 4;
  const int mtb = blockIdx.x * 16 + wv * 4;     // 4 mt tiles per wave
  const _Float16* wrow0 = W + (size_t)((mtb + 0) * 16 + m) * C_DIM + quad * 8;
  const _Float16* wrow1 = W + (size_t)((mtb + 1) * 16 + m) * C_DIM + quad * 8;
  const _Float16* wrow2 = W + (size_t)((mtb + 2) * 16 + m) * C_DIM + quad * 8;
  const _Float16* wrow3 = W + (size_t)((mtb + 3) * 16 + m) * C_DIM + quad * 8;
  const _Float16* lp = &Ld[m * 264 + quad * 8];

  floatx4 acc[4][4];
  #pragma unroll
  for (int j = 0; j < 4; ++j)
    #pragma unroll
    for (int s = 0; s < 4; ++s) acc[j][s] = (floatx4){0.f,0.f,0.f,0.f};

  #pragma unroll
  for (int k0 = 0; k0 < C_DIM; k0 += 32) {
    half8 b0 = *(const half8*)(lp + k0);
    half8 b1 = *(const half8*)(lp + 16 * 264 + k0);
    half8 b2 = *(const half8*)(lp + 32 * 264 + k0);
    half8 b3 = *(const half8*)(lp + 48 * 264 + k0);
    half8 a0 = *(const half8*)(wrow0 + k0);
    half8 a1 = *(const half8*)(wrow1 + k0);
    half8 a2 = *(const half8*)(wrow2 + k0);
    half8 a3 = *(const half8*)(wrow3 + k0);
    acc[0][0] = __builtin_amdgcn_mfma_f32_16x16x32_f16(a0, b0, acc[0][0], 0, 0, 0);
    acc[0][1] = __builtin_amdgcn_mfma_f32_16x16x32_f16(a0, b1, acc[0][1], 0, 0, 0);
    acc[0][2] = __builtin_amdgcn_mfma_f32_16x16x32_f16(a0, b2, acc[0][2], 0, 0, 0);
    acc[0][3] = __builtin_amdgcn_mfma_f32_16x16x32_f16(a0, b3, acc[0][3], 0, 0, 0);
    acc[1][0] = __builtin_amdgcn_mfma_f32_16x16x32_f16(a1, b0, acc[1][0], 0, 0, 0);
    acc[1][1] = __builtin_amdgcn_mfma_f32_16x16x32_f16(a1, b1, acc[1][1], 0, 0, 0);
    acc[1][2] = __builtin_amdgcn_mfma_f32_16x16x32_f16(a1, b2, acc[1][2], 0, 0, 0);
    acc[1][3] = __builtin_amdgcn_mfma_f32_16x16x32_f16(a1, b3, acc[1][3], 0, 0, 0);
    acc[2][0] = __builtin_amdgcn_mfma_f32_16x16x32_f16(a2, b0, acc[2][0], 0, 0, 0);
    acc[2][1] = __builtin_amdgcn_mfma_f32_16x16x32_f16(a2, b1, acc[2][1], 0, 0, 0);
    acc[2][2] = __builtin_amdgcn_mfma_f32_16x16x32_f16(a2, b2, acc[2][2], 0, 0, 0);
    acc[2][3] = __builtin_amdgcn_mfma_f32_16x16x32_f16(a2, b3, acc[2][3], 0, 0, 0);
    acc[3][0] = __builtin_amdgcn_mfma_f32_16x16x32_f16(a3, b0, acc[3][0], 0, 0, 0);
    acc[3][1] = __builtin_amdgcn_mfma_f32_16x16x32_f16(a3, b1, acc[3][1], 0, 0, 0);
    acc[3][2] = __builtin_amdgcn_mfma_f32_16x16x32_f16(a3, b2, acc[3][2], 0, 0, 0);
    acc[3][3] = __builtin_amdgcn_mfma_f32_16x16x32_f16(a3, b3, acc[3][3], 0, 0, 0);
  }

  #pragma unroll
  for (int j = 0; j < 4; ++j) {
    const int ob = (mtb + j) * 16 + quad * 4;
    const float bv0 = bias[ob], bv1 = bias[ob + 1],
                bv2 = bias[ob + 2], bv3 = bias[ob + 3];
    #pragma unroll
    for (int sub = 0; sub < 4; ++sub) {
      int s = s0 + sub * 16 + m;
      float v0 = acc[j][sub][0] + bv0, v1 = acc[j][sub][1] + bv1,
            v2 = acc[j][sub][2] + bv2, v3 = acc[j][sub][3] + bv3;
      if (ob < 512) {                       // q or k: (B,NH,S,hd)
        _Float16* dst = (ob < 256) ? qo : ko_;
        int oo = ob & 255, n = oo >> 5, d0 = oo & 31;
        half4 h = { (_Float16)v0, (_Float16)v1, (_Float16)v2, (_Float16)v3 };
        *(half4*)(dst + (((size_t)b * NHEADS + n) * S_LEN + s) * HDIM + d0) = h;
      } else {                              // v: (B,NH,hd,S)
        int oo = ob - 512, n = oo >> 5, d0 = oo & 31;
        _Float16* dst = vo + ((size_t)b * NHEADS + n) * HDIM * S_LEN + s;
        dst[(size_t)(d0 + 0) * S_LEN] = (_Float16)v0;
        dst[(size_t)(d0 + 1) * S_LEN] = (_Float16)v1;
        dst[(size_t)(d0 + 2) * S_LEN] = (_Float16)v2;
        dst[(size_t)(d0 + 3) * S_LEN] = (_Float16)v3;
      }
    }
  }
}

// ---------------------------------------------------------------- Attention
// 4 waves (256 thr), wave owns 32 q-rows (2 q-frags share every K/V frag).
// 128-key LDS tiles, double-buffered, one barrier per tile. S^T trick:
// QK C-layout == PV B-operand layout of mfma_f32_16x16x16f16.
__global__ __launch_bounds__(256) void attn_kernel(
    const _Float16* __restrict__ q, const _Float16* __restrict__ k,
    const _Float16* __restrict__ v, _Float16* __restrict__ o_t)
{
  __shared__ __align__(16) _Float16 Kl[2][128 * 40];  // (kk, d) stride 40
  __shared__ __align__(16) _Float16 Vl[2][32 * 136];  // (d, kk) stride 136
  const int tid = threadIdx.x;
  const int lane = tid & 63, wv = tid >> 6;           // wv 0..3
  const int m = lane & 15, quad = lane >> 4;
  const int n = blockIdx.y, b = blockIdx.z;
  const int q0 = blockIdx.x * 128 + wv * 32;

  const _Float16* qb = q + (size_t)(b * NHEADS + n) * S_LEN * HDIM;
  const _Float16* kb = k + (size_t)(b * NHEADS + n) * S_LEN * HDIM;
  const _Float16* vb = v + (size_t)(b * NHEADS + n) * HDIM * S_LEN;

  // Q B-frags (QK): lane q=m holds d=quad*8+j
  half8 qf0 = *(const half8*)(qb + (size_t)(q0 + m) * HDIM + quad * 8);
  half8 qf1 = *(const half8*)(qb + (size_t)(q0 + 16 + m) * HDIM + quad * 8);

  // K staging: 128 rows x 32 halfs; lane-pair covers one row (16 halfs each)
  const int krow = wv * 32 + (lane >> 1), kcol = (lane & 1) * 16;
  const _Float16* kg = kb + (size_t)krow * HDIM + kcol;
  const int klds = krow * 40 + kcol;
  // V staging: 32 rows x 128 halfs; 8 threads per row, 16 halfs each
  const int vrow = tid >> 3, vcol = (tid & 7) * 16;
  const _Float16* vg = vb + (size_t)vrow * S_LEN + vcol;
  const int vlds = vrow * 136 + vcol;

  int4 kr0 = *(const int4*)kg;
  int4 kr1 = *(const int4*)(kg + 8);
  int4 vr0 = *(const int4*)vg;
  int4 vr1 = *(const int4*)(vg + 8);
  const _Float16* kgp = kg + 128 * HDIM;
  const _Float16* vgp = vg + 128;

  floatx4 o00 = {0.f,0.f,0.f,0.f}, o10 = o00, o01 = o00, o11 = o00; // [dt][qt]
  float l0 = 0.f, l1 = 0.f;
  const fp16x2 one2 = { (__fp16)1.0f, (__fp16)1.0f };

  #pragma unroll 2
  for (int it = 0; it < 32; ++it) {
    const int bufi = it & 1;
    *(int4*)(&Kl[bufi][klds]) = kr0;
    *(int4*)(&Kl[bufi][klds + 8]) = kr1;
    *(int4*)(&Vl[bufi][vlds]) = vr0;
    *(int4*)(&Vl[bufi][vlds + 8]) = vr1;
    kr0 = *(const int4*)kgp;                 // unconditional prefetch
    kr1 = *(const int4*)(kgp + 8);
    vr0 = *(const int4*)vgp;
    vr1 = *(const int4*)(vgp + 8);
    kgp += 128 * HDIM; vgp += 128;
    __syncthreads();
    const _Float16* Kb = Kl[bufi];
    const _Float16* Vb = Vl[bufi];
    #pragma unroll
    for (int t = 0; t < 8; ++t) {
      half8 kf = *(const half8*)(Kb + (t * 16 + m) * 40 + quad * 8);
      half4 vf0 = *(const half4*)(Vb + m * 136 + t * 16 + quad * 4);
      half4 vf1 = *(const half4*)(Vb + (16 + m) * 136 + t * 16 + quad * 4);
      floatx4 z = {0.f,0.f,0.f,0.f};
      floatx4 s0 = __builtin_amdgcn_mfma_f32_16x16x32_f16(kf, qf0, z, 0, 0, 0);
      floatx4 s1 = __builtin_amdgcn_mfma_f32_16x16x32_f16(kf, qf1, z, 0, 0, 0);
      float e00 = __builtin_amdgcn_exp2f(s0[0]);
      float e01 = __builtin_amdgcn_exp2f(s0[1]);
      float e02 = __builtin_amdgcn_exp2f(s0[2]);
      float e03 = __builtin_amdgcn_exp2f(s0[3]);
      float e10 = __builtin_amdgcn_exp2f(s1[0]);
      float e11 = __builtin_amdgcn_exp2f(s1[1]);
      float e12 = __builtin_amdgcn_exp2f(s1[2]);
      float e13 = __builtin_amdgcn_exp2f(s1[3]);
      half4 p0, p1;
      fp16x2 p0lo = __builtin_amdgcn_cvt_pkrtz(e00, e01);
      fp16x2 p0hi = __builtin_amdgcn_cvt_pkrtz(e02, e03);
      fp16x2 p1lo = __builtin_amdgcn_cvt_pkrtz(e10, e11);
      fp16x2 p1hi = __builtin_amdgcn_cvt_pkrtz(e12, e13);
      *(fp16x2*)&p0 = p0lo; *((fp16x2*)&p0 + 1) = p0hi;
      *(fp16x2*)&p1 = p1lo; *((fp16x2*)&p1 + 1) = p1hi;
      l0 = __builtin_amdgcn_fdot2(p0lo, one2, l0, false);
      l0 = __builtin_amdgcn_fdot2(p0hi, one2, l0, false);
      l1 = __builtin_amdgcn_fdot2(p1lo, one2, l1, false);
      l1 = __builtin_amdgcn_fdot2(p1hi, one2, l1, false);
      o00 = __builtin_amdgcn_mfma_f32_16x16x16f16(vf0, p0, o00, 0, 0, 0);
      o10 = __builtin_amdgcn_mfma_f32_16x16x16f16(vf1, p0, o10, 0, 0, 0);
      o01 = __builtin_amdgcn_mfma_f32_16x16x16f16(vf0, p1, o01, 0, 0, 0);
      o11 = __builtin_amdgcn_mfma_f32_16x16x16f16(vf1, p1, o11, 0, 0, 0);
    }
  }
  // l split across 4 quads (keys) -> reduce
  l0 += __shfl_xor(l0, 16, 64); l0 += __shfl_xor(l0, 32, 64);
  l1 += __shfl_xor(l1, 16, 64); l1 += __shfl_xor(l1, 32, 64);
  const float i0 = 1.f / l0, i1 = 1.f / l1;
  const int c0 = n * HDIM + quad * 4;
  {
    half4 h0 = { (_Float16)(o00[0]*i0), (_Float16)(o00[1]*i0),
                 (_Float16)(o00[2]*i0), (_Float16)(o00[3]*i0) };
    half4 h1 = { (_Float16)(o10[0]*i0), (_Float16)(o10[1]*i0),
                 (_Float16)(o10[2]*i0), (_Float16)(o10[3]*i0) };
    size_t base = ((size_t)b * S_LEN + q0 + m) * C_DIM + c0;
    *(half4*)(o_t + base) = h0;
    *(half4*)(o_t + base + 16) = h1;
  }
  {
    half4 h0 = { (_Float16)(o01[0]*i1), (_Float16)(o01[1]*i1),
                 (_Float16)(o01[2]*i1), (_Float16)(o01[3]*i1) };
    half4 h1 = { (_Float16)(o11[0]*i1), (_Float16)(o11[1]*i1),
                 (_Float16)(o11[2]*i1), (_Float16)(o11[3]*i1) };
    size_t base = ((size_t)b * S_LEN + q0 + 16 + m) * C_DIM + c0;
    *(half4*)(o_t + base) = h0;
    *(half4*)(o_t + base + 16) = h1;
  }
}

// ---------------------------------------------------------------- Proj GEMM
__global__ __launch_bounds__(256) void proj_gemm(
    const _Float16* __restrict__ W, const float* __restrict__ bias,
    const _Float16* __restrict__ o_t, const float* __restrict__ x,
    float* __restrict__ out)
{
  const int tid = threadIdx.x;
  const int lane = tid & 63, wv = tid >> 6;
  const int m = lane & 15, quad = lane >> 4;
  const int mt = blockIdx.x * 4 + wv;  // 0..15
  const int s0 = blockIdx.y * 64;
  const int b = blockIdx.z;
  const int row = mt * 16 + m;
  const _Float16* ob = o_t + (size_t)b * S_LEN * C_DIM;

  const _Float16* wrow = W + (size_t)row * C_DIM + quad * 8;
  const _Float16* h0 = ob + (size_t)(s0 + m) * C_DIM + quad * 8;
  const _Float16* h1 = h0 + 16 * C_DIM;
  const _Float16* h2 = h0 + 32 * C_DIM;
  const _Float16* h3 = h0 + 48 * C_DIM;

  floatx4 acc0 = {0.f,0.f,0.f,0.f}, acc1 = acc0, acc2 = acc0, acc3 = acc0;
  half8 af = *(const half8*)wrow;
  half8 b0 = *(const half8*)h0;
  half8 b1 = *(const half8*)h1;
  half8 b2 = *(const half8*)h2;
  half8 b3 = *(const half8*)h3;
  #pragma unroll
  for (int k0 = 0; k0 < C_DIM; k0 += 32) {
    half8 afn, b0n, b1n, b2n, b3n;
    if (k0 < C_DIM - 32) {
      afn = *(const half8*)(wrow + k0 + 32);
      b0n = *(const half8*)(h0 + k0 + 32);
      b1n = *(const half8*)(h1 + k0 + 32);
      b2n = *(const half8*)(h2 + k0 + 32);
      b3n = *(const half8*)(h3 + k0 + 32);
    }
    acc0 = __builtin_amdgcn_mfma_f32_16x16x32_f16(af, b0, acc0, 0, 0, 0);
    acc1 = __builtin_amdgcn_mfma_f32_16x16x32_f16(af, b1, acc1, 0, 0, 0);
    acc2 = __builtin_amdgcn_mfma_f32_16x16x32_f16(af, b2, acc2, 0, 0, 0);
    acc3 = __builtin_amdgcn_mfma_f32_16x16x32_f16(af, b3, acc3, 0, 0, 0);
    af = afn; b0 = b0n; b1 = b1n; b2 = b2n; b3 = b3n;
  }
  floatx4 accs[4] = {acc0, acc1, acc2, acc3};
  #pragma unroll
  for (int sub = 0; sub < 4; ++sub) {
    int s = s0 + sub * 16 + m;
    #pragma unroll
    for (int r = 0; r < 4; ++r) {
      int c = mt * 16 + quad * 4 + r;
      size_t idx = ((size_t)b * C_DIM + c) * S_LEN + s;
      out[idx] = x[idx] + accs[sub][r] + bias[c];
    }
  }
}

// ---------------------------------------------------------------- launch
extern "C" void kernel_launch(void* const* d_in, const int* in_sizes, int n_in,
                              void* d_out, int out_size, void* d_ws, size_t ws_size,
                              hipStream_t stream) {
  const float* x        = (const float*)d_in[0];
  const float* gn_gamma = (const float*)d_in[1];
  const float* gn_beta  = (const float*)d_in[2];
  const float* qkv_w    = (const float*)d_in[3];
  const float* qkv_b    = (const float*)d_in[4];
  const float* proj_w   = (const float*)d_in[5];
  const float* proj_b   = (const float*)d_in[6];
  float* out = (float*)d_out;

  const size_t n1 = (size_t)2 * S_LEN * C_DIM;   // 2M elems = 4 MB f16
  char* ws = (char*)d_ws;
  _Float16* o_t = (_Float16*)ws;                 // 4 MB (B,S,C)
  _Float16* qx  = o_t + n1;                      // (B,NH,S,hd)
  _Float16* kx  = qx + n1;                       // (B,NH,S,hd)
  _Float16* vx  = kx + n1;                       // (B,NH,hd,S)
  _Float16* wq  = vx + n1;                       // 768x256 f16
  _Float16* wp  = wq + 768 * 256;                // 256x256 f16
  float*    qbias = (float*)(wp + 256 * 256);    // 768 f32
  float*    gstat = qbias + 768;                 // 2*32*2 f32

  prep_stats<<<1091, 256, 0, stream>>>(qkv_w, proj_w, qkv_b, x, wq, wp, qbias, gstat);
  qkv_gn_gemm<<<dim3(3, 64, 2), 256, 0, stream>>>(wq, qbias, x, gn_gamma, gn_beta, gstat, qx, kx, vx);
  attn_kernel<<<dim3(32, 8, 2), 256, 0, stream>>>(qx, kx, vx, o_t);
  proj_gemm<<<dim3(4, 64, 2), 256, 0, stream>>>(wp, proj_b, o_t, x, out);
}

// Round 8
// 166.095 us; speedup vs baseline: 1.0093x; 1.0093x over previous
//
#include <hip/hip_runtime.h>
#include <cstddef>

#define S_LEN 4096
#define C_DIM 256
#define NHEADS 8
#define HDIM 32

typedef __attribute__((ext_vector_type(8))) _Float16 half8;
typedef __attribute__((ext_vector_type(4))) _Float16 half4;
typedef __attribute__((ext_vector_type(2))) _Float16 h2t;
typedef __attribute__((ext_vector_type(2))) __fp16 fp16x2;
typedef __attribute__((ext_vector_type(4))) float floatx4;

// scale * log2(e) folded into W_q and bias_q at prep time
#define SC2F ((float)(0.17677669529663687 * 1.4426950408889634))

// ---------------------------------------------------------------- prep + GN stats (fused)
__global__ __launch_bounds__(256) void prep_stats(
    const float* __restrict__ qkv_w, const float* __restrict__ proj_w,
    const float* __restrict__ qkv_b, const float* __restrict__ x,
    _Float16* __restrict__ wq, _Float16* __restrict__ wp,
    float* __restrict__ qbias, float* __restrict__ gstat)
{
  const int blk = blockIdx.x;
  const int tid = threadIdx.x;
  if (blk < 64) {
    __shared__ float red[2][4];
    const int g = blk & 31, b = blk >> 5;
    const float* xb = x + ((size_t)b * C_DIM + g * 8) * S_LEN;
    const float4* x4 = (const float4*)xb;
    float sum = 0.f, sumsq = 0.f;
    for (int i = tid; i < 8192; i += 256) {
      float4 v = x4[i];
      sum += v.x + v.y + v.z + v.w;
      sumsq += v.x * v.x + v.y * v.y + v.z * v.z + v.w * v.w;
    }
    for (int off = 1; off < 64; off <<= 1) {
      sum += __shfl_xor(sum, off, 64);
      sumsq += __shfl_xor(sumsq, off, 64);
    }
    const int wv = tid >> 6, lane = tid & 63;
    if (lane == 0) { red[0][wv] = sum; red[1][wv] = sumsq; }
    __syncthreads();
    if (tid == 0) {
      float s = red[0][0] + red[0][1] + red[0][2] + red[0][3];
      float sq = red[1][0] + red[1][1] + red[1][2] + red[1][3];
      float mean = s * (1.f / 32768.f);
      float var = sq * (1.f / 32768.f) - mean * mean;
      gstat[((size_t)b * 32 + g) * 2 + 0] = mean;
      gstat[((size_t)b * 32 + g) * 2 + 1] = rsqrtf(var + 1e-6f);
    }
  } else {
    int idx = (blk - 64) * 256 + tid;
    if (idx < 768 * 256) {
      float v = qkv_w[idx];
      if (idx < 256 * 256) v *= SC2F;          // q rows
      wq[idx] = (_Float16)v;
    } else if (idx < 768 * 256 + 256 * 256) {
      int i = idx - 768 * 256;
      wp[i] = (_Float16)proj_w[i];
    } else if (idx < 768 * 256 + 256 * 256 + 768) {
      int i = idx - (768 * 256 + 256 * 256);
      float bv = qkv_b[i];
      if (i < 256) bv *= SC2F;
      qbias[i] = bv;
    }
  }
}

// ---------------------------------------------------------------- QKV GEMM + inline GN
// Wave owns 2 mt-tiles: 8 MFMA per 4 B ds_reads; grid.x=6 -> 768 blocks
// (12 waves/CU) with 6x GN redundancy.
__global__ __launch_bounds__(256) void qkv_gn_gemm(
    const _Float16* __restrict__ W, const float* __restrict__ bias,
    const float* __restrict__ x, const float* __restrict__ gamma,
    const float* __restrict__ beta, const float* __restrict__ gstat,
    _Float16* __restrict__ qo, _Float16* __restrict__ ko_,
    _Float16* __restrict__ vo)
{
  __shared__ __align__(16) _Float16 Ld[64 * 264];   // [s][c], stride 264
  const int tid = threadIdx.x;
  const int b = blockIdx.z;
  const int s0 = blockIdx.y * 64;

  {  // ---- inline GN apply: x (c,s) -> Ld[s][c] f16
    const int c0 = (tid & 127) * 2, c1 = c0 + 1;
    const int sh = tid >> 7;                         // s-half 0/1
    const int g = c0 >> 3;
    const float mean = gstat[((size_t)b * 32 + g) * 2 + 0];
    const float rstd = gstat[((size_t)b * 32 + g) * 2 + 1];
    const float ga0 = gamma[c0] * rstd, be0 = beta[c0] - mean * ga0;
    const float ga1 = gamma[c1] * rstd, be1 = beta[c1] - mean * ga1;
    const float4* xa = (const float4*)(x + ((size_t)b * C_DIM + c0) * S_LEN + s0 + sh * 32);
    const float4* xc = (const float4*)(x + ((size_t)b * C_DIM + c1) * S_LEN + s0 + sh * 32);
    #pragma unroll
    for (int j = 0; j < 8; ++j) {
      float4 a = xa[j], c = xc[j];
      int sl = sh * 32 + j * 4;
      *(h2t*)&Ld[(sl + 0) * 264 + c0] = (h2t){ (_Float16)(a.x * ga0 + be0), (_Float16)(c.x * ga1 + be1) };
      *(h2t*)&Ld[(sl + 1) * 264 + c0] = (h2t){ (_Float16)(a.y * ga0 + be0), (_Float16)(c.y * ga1 + be1) };
      *(h2t*)&Ld[(sl + 2) * 264 + c0] = (h2t){ (_Float16)(a.z * ga0 + be0), (_Float16)(c.z * ga1 + be1) };
      *(h2t*)&Ld[(sl + 3) * 264 + c0] = (h2t){ (_Float16)(a.w * ga0 + be0), (_Float16)(c.w * ga1 + be1) };
    }
  }
  __syncthreads();

  const int lane = tid & 63, wv = tid >> 6;
  const int m = lane & 15, quad = lane >> 4;
  const int mtb = blockIdx.x * 8 + wv * 2;      // 2 mt tiles per wave
  const _Float16* wrow0 = W + (size_t)((mtb + 0) * 16 + m) * C_DIM + quad * 8;
  const _Float16* wrow1 = W + (size_t)((mtb + 1) * 16 + m) * C_DIM + quad * 8;
  const _Float16* lp = &Ld[m * 264 + quad * 8];

  floatx4 acc[2][4];
  #pragma unroll
  for (int j = 0; j < 2; ++j)
    #pragma unroll
    for (int s = 0; s < 4; ++s) acc[j][s] = (floatx4){0.f,0.f,0.f,0.f};

  #pragma unroll
  for (int k0 = 0; k0 < C_DIM; k0 += 32) {
    half8 b0 = *(const half8*)(lp + k0);
    half8 b1 = *(const half8*)(lp + 16 * 264 + k0);
    half8 b2 = *(const half8*)(lp + 32 * 264 + k0);
    half8 b3 = *(const half8*)(lp + 48 * 264 + k0);
    half8 a0 = *(const half8*)(wrow0 + k0);
    half8 a1 = *(const half8*)(wrow1 + k0);
    acc[0][0] = __builtin_amdgcn_mfma_f32_16x16x32_f16(a0, b0, acc[0][0], 0, 0, 0);
    acc[0][1] = __builtin_amdgcn_mfma_f32_16x16x32_f16(a0, b1, acc[0][1], 0, 0, 0);
    acc[0][2] = __builtin_amdgcn_mfma_f32_16x16x32_f16(a0, b2, acc[0][2], 0, 0, 0);
    acc[0][3] = __builtin_amdgcn_mfma_f32_16x16x32_f16(a0, b3, acc[0][3], 0, 0, 0);
    acc[1][0] = __builtin_amdgcn_mfma_f32_16x16x32_f16(a1, b0, acc[1][0], 0, 0, 0);
    acc[1][1] = __builtin_amdgcn_mfma_f32_16x16x32_f16(a1, b1, acc[1][1], 0, 0, 0);
    acc[1][2] = __builtin_amdgcn_mfma_f32_16x16x32_f16(a1, b2, acc[1][2], 0, 0, 0);
    acc[1][3] = __builtin_amdgcn_mfma_f32_16x16x32_f16(a1, b3, acc[1][3], 0, 0, 0);
  }

  #pragma unroll
  for (int j = 0; j < 2; ++j) {
    const int ob = (mtb + j) * 16 + quad * 4;
    const float bv0 = bias[ob], bv1 = bias[ob + 1],
                bv2 = bias[ob + 2], bv3 = bias[ob + 3];
    #pragma unroll
    for (int sub = 0; sub < 4; ++sub) {
      int s = s0 + sub * 16 + m;
      float v0 = acc[j][sub][0] + bv0, v1 = acc[j][sub][1] + bv1,
            v2 = acc[j][sub][2] + bv2, v3 = acc[j][sub][3] + bv3;
      if (ob < 512) {                       // q or k: (B,NH,S,hd)
        _Float16* dst = (ob < 256) ? qo : ko_;
        int oo = ob & 255, n = oo >> 5, d0 = oo & 31;
        half4 h = { (_Float16)v0, (_Float16)v1, (_Float16)v2, (_Float16)v3 };
        *(half4*)(dst + (((size_t)b * NHEADS + n) * S_LEN + s) * HDIM + d0) = h;
      } else {                              // v: (B,NH,hd,S)
        int oo = ob - 512, n = oo >> 5, d0 = oo & 31;
        _Float16* dst = vo + ((size_t)b * NHEADS + n) * HDIM * S_LEN + s;
        dst[(size_t)(d0 + 0) * S_LEN] = (_Float16)v0;
        dst[(size_t)(d0 + 1) * S_LEN] = (_Float16)v1;
        dst[(size_t)(d0 + 2) * S_LEN] = (_Float16)v2;
        dst[(size_t)(d0 + 3) * S_LEN] = (_Float16)v3;
      }
    }
  }
}

// ---------------------------------------------------------------- Attention
// R6 structure + key-split: 8 waves/block, 16 q/wave; each block handles a
// 2048-key half, writing unnormalized partial (o f16, l f32). 2048 blocks...
// grid (64,8,2) = 1024 blocks -> 32 waves/CU occupancy cap (was 16).
__global__ __launch_bounds__(512) void attn_kernel(
    const _Float16* __restrict__ q, const _Float16* __restrict__ k,
    const _Float16* __restrict__ v, _Float16* __restrict__ po,
    float* __restrict__ pl)
{
  __shared__ __align__(16) _Float16 Kl[2][64 * 40];  // (kk, d) stride 40
  __shared__ __align__(16) _Float16 Vl[2][32 * 68];  // (d, kk) stride 68
  const int tid = threadIdx.x;
  const int lane = tid & 63, wv = tid >> 6;          // wv 0..7
  const int m = lane & 15, quad = lane >> 4;
  const int n = blockIdx.y, b = blockIdx.z;
  const int qc = blockIdx.x >> 1, kh = blockIdx.x & 1;
  const int q0 = qc * 128 + wv * 16;
  const int bh = b * NHEADS + n;

  const _Float16* qb = q + (size_t)bh * S_LEN * HDIM;
  const _Float16* kb = k + (size_t)bh * S_LEN * HDIM + (size_t)kh * 2048 * HDIM;
  const _Float16* vb = v + (size_t)bh * HDIM * S_LEN + (size_t)kh * 2048;

  // Q B-frag (QK): lane q=m holds d=quad*8+j
  half8 qf = *(const half8*)(qb + (size_t)(q0 + m) * HDIM + quad * 8);

  // staging: wave wv stages K rows [wv*8,+8), V rows [wv*4,+4); 8B per lane
  const int krow = wv * 8 + (lane >> 3), kc = (lane & 7) * 4;
  const int vrow = wv * 4 + (lane >> 4), vc = (lane & 15) * 4;
  const _Float16* kg = kb + (size_t)krow * HDIM + kc;
  const _Float16* vg = vb + (size_t)vrow * S_LEN + vc;
  const int klds = krow * 40 + kc;
  const int vlds = vrow * 68 + vc;

  int2 kreg = *(const int2*)kg;
  int2 vreg = *(const int2*)vg;
  const _Float16* kgp = kg + 64 * HDIM;
  const _Float16* vgp = vg + 64;

  floatx4 o0 = {0.f,0.f,0.f,0.f}, o1 = o0;   // d-tiles 0/1 for this wave's 16 q
  float l0 = 0.f;
  const fp16x2 one2 = { (__fp16)1.0f, (__fp16)1.0f };

  #pragma unroll 2
  for (int it = 0; it < 32; ++it) {          // 32 x 64 keys = 2048 (half)
    const int bufi = it & 1;
    *(int2*)(&Kl[bufi][klds]) = kreg;
    *(int2*)(&Vl[bufi][vlds]) = vreg;
    kreg = *(const int2*)kgp; kgp += 64 * HDIM;   // unconditional prefetch
    vreg = *(const int2*)vgp; vgp += 64;
    __syncthreads();
    const _Float16* Kb = Kl[bufi];
    const _Float16* Vb = Vl[bufi];
    #pragma unroll
    for (int t = 0; t < 4; ++t) {
      half8 kf = *(const half8*)(Kb + (t * 16 + m) * 40 + quad * 8);
      half4 vf0 = *(const half4*)(Vb + m * 68 + t * 16 + quad * 4);
      half4 vf1 = *(const half4*)(Vb + (16 + m) * 68 + t * 16 + quad * 4);
      floatx4 z = {0.f,0.f,0.f,0.f};
      floatx4 s0 = __builtin_amdgcn_mfma_f32_16x16x32_f16(kf, qf, z, 0, 0, 0);
      float e0 = __builtin_amdgcn_exp2f(s0[0]);
      float e1 = __builtin_amdgcn_exp2f(s0[1]);
      float e2 = __builtin_amdgcn_exp2f(s0[2]);
      float e3 = __builtin_amdgcn_exp2f(s0[3]);
      half4 p0;
      fp16x2 plo = __builtin_amdgcn_cvt_pkrtz(e0, e1);
      fp16x2 phi = __builtin_amdgcn_cvt_pkrtz(e2, e3);
      *(fp16x2*)&p0 = plo;
      *((fp16x2*)&p0 + 1) = phi;
      l0 = __builtin_amdgcn_fdot2(plo, one2, l0, false);
      l0 = __builtin_amdgcn_fdot2(phi, one2, l0, false);
      o0 = __builtin_amdgcn_mfma_f32_16x16x16f16(vf0, p0, o0, 0, 0, 0);
      o1 = __builtin_amdgcn_mfma_f32_16x16x16f16(vf1, p0, o1, 0, 0, 0);
    }
  }
  // l split across 4 quads (keys) -> reduce
  l0 += __shfl_xor(l0, 16, 64);
  l0 += __shfl_xor(l0, 32, 64);
  // partial store (unnormalized): po[kh][bh][q][d] f16, pl[kh][bh*4096+q]
  _Float16* poh = po + (size_t)kh * 2097152 + ((size_t)bh * S_LEN + q0 + m) * HDIM;
  half4 h0 = { (_Float16)o0[0], (_Float16)o0[1], (_Float16)o0[2], (_Float16)o0[3] };
  half4 h1 = { (_Float16)o1[0], (_Float16)o1[1], (_Float16)o1[2], (_Float16)o1[3] };
  *(half4*)(poh + quad * 4) = h0;
  *(half4*)(poh + 16 + quad * 4) = h1;
  if (quad == 0) pl[(size_t)kh * 65536 + (size_t)bh * S_LEN + q0 + m] = l0;
}

// ---------------------------------------------------------------- merge partials
// o_t[b][s][n*32+d] = (po0+po1) / (l0+l1); 64 q-rows per block
__global__ __launch_bounds__(256) void attn_merge(
    const _Float16* __restrict__ po, const float* __restrict__ pl,
    _Float16* __restrict__ o_t)
{
  const int tid = threadIdx.x;
  const int row = blockIdx.x * 64 + (tid >> 2);     // 0..65535
  const int d0 = (tid & 3) * 8;
  const int bh = row >> 12, qq = row & 4095;
  const int b = bh >> 3, n = bh & 7;
  const float l = pl[row] + pl[65536 + row];
  const float inv = 1.f / l;
  half8 a = *(const half8*)(po + (size_t)row * HDIM + d0);
  half8 c = *(const half8*)(po + 2097152 + (size_t)row * HDIM + d0);
  half8 o;
  #pragma unroll
  for (int i = 0; i < 8; ++i)
    o[i] = (_Float16)(((float)a[i] + (float)c[i]) * inv);
  *(half8*)(o_t + ((size_t)b * S_LEN + qq) * C_DIM + n * HDIM + d0) = o;
}

// ---------------------------------------------------------------- Proj GEMM
__global__ __launch_bounds__(256) void proj_gemm(
    const _Float16* __restrict__ W, const float* __restrict__ bias,
    const _Float16* __restrict__ o_t, const float* __restrict__ x,
    float* __restrict__ out)
{
  const int tid = threadIdx.x;
  const int lane = tid & 63, wv = tid >> 6;
  const int m = lane & 15, quad = lane >> 4;
  const int mt = blockIdx.x * 4 + wv;  // 0..15
  const int s0 = blockIdx.y * 64;
  const int b = blockIdx.z;
  const int row = mt * 16 + m;
  const _Float16* ob = o_t + (size_t)b * S_LEN * C_DIM;

  const _Float16* wrow = W + (size_t)row * C_DIM + quad * 8;
  const _Float16* h0 = ob + (size_t)(s0 + m) * C_DIM + quad * 8;
  const _Float16* h1 = h0 + 16 * C_DIM;
  const _Float16* h2 = h0 + 32 * C_DIM;
  const _Float16* h3 = h0 + 48 * C_DIM;

  floatx4 acc0 = {0.f,0.f,0.f,0.f}, acc1 = acc0, acc2 = acc0, acc3 = acc0;
  half8 af = *(const half8*)wrow;
  half8 b0 = *(const half8*)h0;
  half8 b1 = *(const half8*)h1;
  half8 b2 = *(const half8*)h2;
  half8 b3 = *(const half8*)h3;
  #pragma unroll
  for (int k0 = 0; k0 < C_DIM; k0 += 32) {
    half8 afn, b0n, b1n, b2n, b3n;
    if (k0 < C_DIM - 32) {
      afn = *(const half8*)(wrow + k0 + 32);
      b0n = *(const half8*)(h0 + k0 + 32);
      b1n = *(const half8*)(h1 + k0 + 32);
      b2n = *(const half8*)(h2 + k0 + 32);
      b3n = *(const half8*)(h3 + k0 + 32);
    }
    acc0 = __builtin_amdgcn_mfma_f32_16x16x32_f16(af, b0, acc0, 0, 0, 0);
    acc1 = __builtin_amdgcn_mfma_f32_16x16x32_f16(af, b1, acc1, 0, 0, 0);
    acc2 = __builtin_amdgcn_mfma_f32_16x16x32_f16(af, b2, acc2, 0, 0, 0);
    acc3 = __builtin_amdgcn_mfma_f32_16x16x32_f16(af, b3, acc3, 0, 0, 0);
    af = afn; b0 = b0n; b1 = b1n; b2 = b2n; b3 = b3n;
  }
  floatx4 accs[4] = {acc0, acc1, acc2, acc3};
  #pragma unroll
  for (int sub = 0; sub < 4; ++sub) {
    int s = s0 + sub * 16 + m;
    #pragma unroll
    for (int r = 0; r < 4; ++r) {
      int c = mt * 16 + quad * 4 + r;
      size_t idx = ((size_t)b * C_DIM + c) * S_LEN + s;
      out[idx] = x[idx] + accs[sub][r] + bias[c];
    }
  }
}

// ---------------------------------------------------------------- launch
extern "C" void kernel_launch(void* const* d_in, const int* in_sizes, int n_in,
                              void* d_out, int out_size, void* d_ws, size_t ws_size,
                              hipStream_t stream) {
  const float* x        = (const float*)d_in[0];
  const float* gn_gamma = (const float*)d_in[1];
  const float* gn_beta  = (const float*)d_in[2];
  const float* qkv_w    = (const float*)d_in[3];
  const float* qkv_b    = (const float*)d_in[4];
  const float* proj_w   = (const float*)d_in[5];
  const float* proj_b   = (const float*)d_in[6];
  float* out = (float*)d_out;

  const size_t n1 = (size_t)2 * S_LEN * C_DIM;   // 2M elems = 4 MB f16
  char* ws = (char*)d_ws;
  _Float16* o_t = (_Float16*)ws;                 // 4 MB (B,S,C)
  _Float16* qx  = o_t + n1;                      // (B,NH,S,hd)
  _Float16* kx  = qx + n1;                       // (B,NH,S,hd)
  _Float16* vx  = kx + n1;                       // (B,NH,hd,S)
  _Float16* wq  = vx + n1;                       // 768x256 f16
  _Float16* wp  = wq + 768 * 256;                // 256x256 f16
  float*    qbias = (float*)(wp + 256 * 256);    // 768 f32
  float*    gstat = qbias + 768;                 // 128 f32
  _Float16* po  = (_Float16*)(gstat + 128);      // 2 x 2M f16 = 8 MB
  float*    pl  = (float*)(po + 2 * n1);         // 2 x 64K f32 = 512 KB

  prep_stats<<<1091, 256, 0, stream>>>(qkv_w, proj_w, qkv_b, x, wq, wp, qbias, gstat);
  qkv_gn_gemm<<<dim3(6, 64, 2), 256, 0, stream>>>(wq, qbias, x, gn_gamma, gn_beta, gstat, qx, kx, vx);
  attn_kernel<<<dim3(64, 8, 2), 512, 0, stream>>>(qx, kx, vx, po, pl);
  attn_merge<<<1024, 256, 0, stream>>>(po, pl, o_t);
  proj_gemm<<<dim3(4, 64, 2), 256, 0, stream>>>(wp, proj_b, o_t, x, out);
}